// Round 12
// baseline (206.430 us; speedup 1.0000x reference)
//
#include <hip/hip_runtime.h>

#define SS 1024
#define GG 10
#define FF 5
#define BB 8
#define CC 3
#define KK (2 * FF + 1)

// ---------------------------------------------------------------------------
// Kernel 1: smooth the (B,1,G,G) offset grids with an 11x11 gaussian
// (edge-padded), scale by max_offset, clip, store field [B][2][G][G] in ws.
// ---------------------------------------------------------------------------
__global__ __launch_bounds__(256) void rds_smooth_kernel(
    const float* __restrict__ ox, const float* __restrict__ oy,
    const float* __restrict__ w, const void* __restrict__ max_move_p,
    float* __restrict__ gs)
{
    int idx = blockIdx.x * 256 + threadIdx.x;
    if (idx >= BB * 2 * GG * GG) return;
    int j  = idx % GG;
    int i  = (idx / GG) % GG;
    int ch = (idx / (GG * GG)) % 2;
    int b  = idx / (2 * GG * GG);

    const float* o = (ch == 0 ? ox : oy) + b * GG * GG;

    // max_move: python scalar; hedge int32 vs float32 storage
    int mi = *(const int*)max_move_p;
    float mv = (mi >= -100000 && mi <= 100000) ? (float)mi : __int_as_float(mi);
    float max_offset = 2.0f * mv / (float)SS;

    float acc = 0.0f;
    for (int u = 0; u < KK; ++u) {
        int yy = min(max(i + u - FF, 0), GG - 1);
        for (int v = 0; v < KK; ++v) {
            int xx = min(max(j + v - FF, 0), GG - 1);
            acc += o[yy * GG + xx] * w[u * KK + v];
        }
    }
    acc *= max_offset;
    acc = fminf(fmaxf(acc, -max_offset), max_offset);
    gs[idx] = acc;
}

// ---------------------------------------------------------------------------
// Kernel 2: 4-row x 256-col tile per block.
//
// R11: R10's 12B global_load_lds FAILED correctness (absmax 6.5) — the 12B
// LDS dest stride was the one UNVERIFIED semantic (guide verifies lane*size
// only for 4B/m03 and 16B/m97; dwordx3 likely strides lane*16). Repair with
// the m03-verified 4B form only: each corner-pair element is its own 4B DMA.
//
// Standing R10 theory (unmeasured, not falsified): R9 showed per-wave
// lifetime ~23k cy = 16 gathers x ~1400cy loaded-latency with G~1 in flight
// — the VGPR=36 schedule serializes gathers (R4/R6: compiler refuses to
// hold gather results in VGPRs; forcing spills). DMA-to-LDS sidesteps the
// register file: zero data-VGPRs, all 16 loads/channel in flight.
//
// LDS: stage[wave][slot 0..15][lane] floats, slot region 256B, read back at
// stride-1 dword (2 lanes/bank = free). Slots: top e0/e1 = 2p/2p+1,
// bottom e0/e1 = 8+2p/9+2p. Per channel: 16 DMA -> vmcnt(0) -> consume
// (+ lgkmcnt(0) before next channel's DMA overwrites slots).
//
// Keeps: weight remap (d = x0-bclamp), row masks, nontemporal stores,
// identity block mapping (R9: XCD swizzle regressed, reverted).
// ---------------------------------------------------------------------------
#define GLD4(g, l) __builtin_amdgcn_global_load_lds( \
    (const __attribute__((address_space(1))) unsigned int*)(const void*)(g), \
    (__attribute__((address_space(3))) unsigned int*)(void*)(l), 4, 0, 0)

__global__ __launch_bounds__(256, 4) void rds_deform_kernel(
    const float* __restrict__ x, const float* __restrict__ gs,
    float* __restrict__ out)
{
    int wg    = blockIdx.x;
    int xseg  = wg & 3;
    int ytile = (wg >> 2) & 255;     // SS/4 = 256 tiles
    int b     = wg >> 10;
    int tid   = threadIdx.x;
    int ybase = ytile << 2;
    int xc    = (xseg << 8) + tid;
    int wid   = tid >> 6;
    int lane  = tid & 63;

    __shared__ float rowf[4][2][GG];
    __shared__ float stage[4 * 16 * 64];   // [wave][slot][lane] = 16 KB

    const float GdS = (float)GG / (float)SS;

    // Fill 4 rows x 2 channels x 10 cols of y-interpolated field
    if (tid < 80) {
        int p  = tid / 20;
        int r  = tid - p * 20;
        int ch = r / GG;
        int j  = r - ch * GG;
        int y  = ybase + p;
        float sy  = fmaxf(((float)y + 0.5f) * GdS - 0.5f, 0.0f);
        int   i0y = min((int)sy, GG - 1);
        int   i1y = min(i0y + 1, GG - 1);
        float wyu = sy - (float)i0y;
        const float* gb = gs + (b * 2 + ch) * GG * GG;
        rowf[p][ch][j] = gb[i0y * GG + j] + wyu * (gb[i1y * GG + j] - gb[i0y * GG + j]);
    }
    __syncthreads();

    // ---- x-direction quantities: once per thread ----
    float sx  = fmaxf(((float)xc + 0.5f) * GdS - 0.5f, 0.0f);
    int   i0x = min((int)sx, GG - 1);
    int   i1x = min(i0x + 1, GG - 1);
    float wxu = sx - (float)i0x;
    float pxc = (float)xc * (2.0f / (float)(SS - 1)) - 1.0f;

    int   oa[4], ob[4];          // float offsets of pair base, rows cy0/cy1
    float wxa[4], wxb[4];        // horizontal weights for pair elements
    float wya[4], wyb[4];        // vertical weights incl. row masks

    #pragma unroll
    for (int p = 0; p < 4; ++p) {
        float r0a = rowf[p][0][i0x], r0b = rowf[p][0][i1x];
        float r1a = rowf[p][1][i0x], r1b = rowf[p][1][i1x];
        float gxv = r0a + wxu * (r0b - r0a);
        float gyv = r1a + wxu * (r1b - r1a);

        float py  = (float)(ybase + p) * (2.0f / (float)(SS - 1)) - 1.0f;
        float gr0 = fminf(fmaxf(gxv + pxc, -1.0f), 1.0f);
        float gr1 = fminf(fmaxf(gyv + py,  -1.0f), 1.0f);

        // ((gr+1)*S-1)/2 == gr*512 + 511.5
        float ix = gr0 * 512.0f + 511.5f;
        float iy = gr1 * 512.0f + 511.5f;

        int   x0 = (int)floorf(ix);      // in [-1, SS-1] after clip
        int   y0 = (int)floorf(iy);
        int   y1 = y0 + 1;
        float wx = ix - (float)x0;
        float wy = iy - (float)y0;

        // pair at [bclamp, bclamp+1], bclamp=clamp(x0,0,S-2); d in {-1,0,1}
        int bclamp = min(max(x0, 0), SS - 2);
        int d      = x0 - bclamp;
        // d==0 : (1-wx)*e0 + wx*e1   (both corners in range)
        // d==-1: x0=-1 -> corner x1=0 is e0  -> wx*e0
        // d==+1: x0=SS-1 -> corner x0 is e1  -> (1-wx)*e1
        wxa[p] = (d == 0) ? (1.0f - wx) : ((d < 0) ? wx : 0.0f);
        wxb[p] = (d == 0) ? wx          : ((d < 0) ? 0.0f : (1.0f - wx));

        float my0 = ((unsigned)y0 < (unsigned)SS) ? 1.0f : 0.0f;
        float my1 = ((unsigned)y1 < (unsigned)SS) ? 1.0f : 0.0f;
        wya[p] = (1.0f - wy) * my0;
        wyb[p] = wy * my1;

        int cy0 = min(max(y0, 0), SS - 1);
        int cy1 = min(max(y1, 0), SS - 1);
        oa[p] = cy0 * SS + bclamp;
        ob[p] = cy1 * SS + bclamp;
    }

    const float* xb = x + (size_t)b * CC * SS * SS;
    size_t obase = (((size_t)b * CC) * SS + ybase) * SS + xc;
    int wbase = wid * (16 * 64);         // this wave's stage region (floats)

    #pragma unroll
    for (int c = 0; c < CC; ++c) {
        const float* img = xb + (size_t)c * SS * SS;

        // ---- issue 16 x 4B DMA gathers; zero data-VGPRs, all in flight ----
        #pragma unroll
        for (int p = 0; p < 4; ++p) {
            GLD4(img + oa[p],     &stage[wbase + (2 * p) * 64]);
            GLD4(img + oa[p] + 1, &stage[wbase + (2 * p + 1) * 64]);
            GLD4(img + ob[p],     &stage[wbase + (8 + 2 * p) * 64]);
            GLD4(img + ob[p] + 1, &stage[wbase + (9 + 2 * p) * 64]);
        }
        asm volatile("s_waitcnt vmcnt(0)" ::: "memory");
        __builtin_amdgcn_sched_barrier(0);

        // ---- consume from LDS (stride-1 dword: conflict-free) + store ----
        #pragma unroll
        for (int p = 0; p < 4; ++p) {
            float a0 = stage[wbase + (2 * p) * 64 + lane];
            float a1 = stage[wbase + (2 * p + 1) * 64 + lane];
            float b0 = stage[wbase + (8 + 2 * p) * 64 + lane];
            float b1 = stage[wbase + (9 + 2 * p) * 64 + lane];
            float v = wya[p] * (a0 * wxa[p] + a1 * wxb[p])
                    + wyb[p] * (b0 * wxa[p] + b1 * wxb[p]);
            __builtin_nontemporal_store(
                v, out + obase + (size_t)c * SS * SS + (size_t)(p * SS));
        }
        // ds_reads must land before next channel's DMA overwrites the slots
        asm volatile("s_waitcnt lgkmcnt(0)" ::: "memory");
        __builtin_amdgcn_sched_barrier(0);
    }
}

extern "C" void kernel_launch(void* const* d_in, const int* in_sizes, int n_in,
                              void* d_out, int out_size, void* d_ws, size_t ws_size,
                              hipStream_t stream) {
    const float* x        = (const float*)d_in[0];
    const float* offset_x = (const float*)d_in[1];
    const float* offset_y = (const float*)d_in[2];
    const float* weight   = (const float*)d_in[3];
    const void*  max_move = d_in[4];
    float* out = (float*)d_out;
    float* gs  = (float*)d_ws;   // [B][2][G][G] smoothed, scaled, clipped field

    int n1 = BB * 2 * GG * GG;   // 1600
    rds_smooth_kernel<<<(n1 + 255) / 256, 256, 0, stream>>>(
        offset_x, offset_y, weight, max_move, gs);

    int nblocks = BB * (SS / 4) * 4;   // 8192: (b, ytile, xseg)
    rds_deform_kernel<<<nblocks, 256, 0, stream>>>(x, gs, out);
}

// Round 15
// 196.168 us; speedup vs baseline: 1.0523x; 1.0523x over previous
//
#include <hip/hip_runtime.h>

#define SS 1024
#define GG 10
#define FF 5
#define BB 8
#define CC 3
#define KK (2 * FF + 1)

typedef float f32x2 __attribute__((ext_vector_type(2)));

// ---------------------------------------------------------------------------
// Kernel 1: smooth the (B,1,G,G) offset grids with an 11x11 gaussian
// (edge-padded), scale by max_offset, clip, store field [B][2][G][G] in ws.
// ---------------------------------------------------------------------------
__global__ __launch_bounds__(256) void rds_smooth_kernel(
    const float* __restrict__ ox, const float* __restrict__ oy,
    const float* __restrict__ w, const void* __restrict__ max_move_p,
    float* __restrict__ gs)
{
    int idx = blockIdx.x * 256 + threadIdx.x;
    if (idx >= BB * 2 * GG * GG) return;
    int j  = idx % GG;
    int i  = (idx / GG) % GG;
    int ch = (idx / (GG * GG)) % 2;
    int b  = idx / (2 * GG * GG);

    const float* o = (ch == 0 ? ox : oy) + b * GG * GG;

    // max_move: python scalar; hedge int32 vs float32 storage
    int mi = *(const int*)max_move_p;
    float mv = (mi >= -100000 && mi <= 100000) ? (float)mi : __int_as_float(mi);
    float max_offset = 2.0f * mv / (float)SS;

    float acc = 0.0f;
    for (int u = 0; u < KK; ++u) {
        int yy = min(max(i + u - FF, 0), GG - 1);
        for (int v = 0; v < KK; ++v) {
            int xx = min(max(j + v - FF, 0), GG - 1);
            acc += o[yy * GG + xx] * w[u * KK + v];
        }
    }
    acc *= max_offset;
    acc = fminf(fmaxf(acc, -max_offset), max_offset);
    gs[idx] = acc;
}

// ---------------------------------------------------------------------------
// Kernel 2: 4-row x 256-col tile per block.
//
// R12 model (fits all 7 measured configs): per-gather cost ~ full loaded
// latency with tiny effective G. R8's "fixup" branches are lane-divergent
// -> taken with P~1 at wave level, so they never cut instruction count and
// their copy-then-overwrite pattern (lb0=la1; if(...) reload) chains loads
// serially. R11's LDS-DMA guaranteed G=16 but the divergent-return path
// made it slower (74.5 vs 61.6). Never tested: plain independent VGPR
// gathers with an RA budget that allows a batch. R6's 48-output asm spilled
// under launch_bounds(256,4); 8 outputs (16 VGPRs) per channel under
// launch_bounds(256,2) (VGPR cap 256) must allocate.
//
// Per channel: 8 volatile-asm global_load_dwordx2 (program-order pinned,
// un-sinkable, G=8) -> s_waitcnt vmcnt(0) -> sched_barrier(0) (rule #18:
// VALU can hoist past asm waitcnt) -> FMAs + nontemporal stores.
// Row-sharing dropped (proven ~neutral, causes the copy-chains).
//
// Keeps: weight remap (d = x0-bclamp), row masks, nontemporal stores,
// identity block mapping (R9: XCD swizzle regressed, reverted).
// ---------------------------------------------------------------------------
__global__ __launch_bounds__(256, 2) void rds_deform_kernel(
    const float* __restrict__ x, const float* __restrict__ gs,
    float* __restrict__ out)
{
    int wg    = blockIdx.x;
    int xseg  = wg & 3;
    int ytile = (wg >> 2) & 255;     // SS/4 = 256 tiles
    int b     = wg >> 10;
    int tid   = threadIdx.x;
    int ybase = ytile << 2;
    int xc    = (xseg << 8) + tid;

    __shared__ float rowf[4][2][GG];

    const float GdS = (float)GG / (float)SS;

    // Fill 4 rows x 2 channels x 10 cols of y-interpolated field
    if (tid < 80) {
        int p  = tid / 20;
        int r  = tid - p * 20;
        int ch = r / GG;
        int j  = r - ch * GG;
        int y  = ybase + p;
        float sy  = fmaxf(((float)y + 0.5f) * GdS - 0.5f, 0.0f);
        int   i0y = min((int)sy, GG - 1);
        int   i1y = min(i0y + 1, GG - 1);
        float wyu = sy - (float)i0y;
        const float* gb = gs + (b * 2 + ch) * GG * GG;
        rowf[p][ch][j] = gb[i0y * GG + j] + wyu * (gb[i1y * GG + j] - gb[i0y * GG + j]);
    }
    __syncthreads();

    // ---- x-direction quantities: once per thread ----
    float sx  = fmaxf(((float)xc + 0.5f) * GdS - 0.5f, 0.0f);
    int   i0x = min((int)sx, GG - 1);
    int   i1x = min(i0x + 1, GG - 1);
    float wxu = sx - (float)i0x;
    float pxc = (float)xc * (2.0f / (float)(SS - 1)) - 1.0f;

    int   oa[4], ob[4];          // float offsets of pair base, rows cy0/cy1
    float wxa[4], wxb[4];        // horizontal weights for pair elements
    float wya[4], wyb[4];        // vertical weights incl. row masks

    #pragma unroll
    for (int p = 0; p < 4; ++p) {
        float r0a = rowf[p][0][i0x], r0b = rowf[p][0][i1x];
        float r1a = rowf[p][1][i0x], r1b = rowf[p][1][i1x];
        float gxv = r0a + wxu * (r0b - r0a);
        float gyv = r1a + wxu * (r1b - r1a);

        float py  = (float)(ybase + p) * (2.0f / (float)(SS - 1)) - 1.0f;
        float gr0 = fminf(fmaxf(gxv + pxc, -1.0f), 1.0f);
        float gr1 = fminf(fmaxf(gyv + py,  -1.0f), 1.0f);

        // ((gr+1)*S-1)/2 == gr*512 + 511.5
        float ix = gr0 * 512.0f + 511.5f;
        float iy = gr1 * 512.0f + 511.5f;

        int   x0 = (int)floorf(ix);      // in [-1, SS-1] after clip
        int   y0 = (int)floorf(iy);
        int   y1 = y0 + 1;
        float wx = ix - (float)x0;
        float wy = iy - (float)y0;

        // pair at [bclamp, bclamp+1], bclamp=clamp(x0,0,S-2); d in {-1,0,1}
        int bclamp = min(max(x0, 0), SS - 2);
        int d      = x0 - bclamp;
        // d==0 : (1-wx)*e0 + wx*e1   (both corners in range)
        // d==-1: x0=-1 -> corner x1=0 is e0  -> wx*e0
        // d==+1: x0=SS-1 -> corner x0 is e1  -> (1-wx)*e1
        wxa[p] = (d == 0) ? (1.0f - wx) : ((d < 0) ? wx : 0.0f);
        wxb[p] = (d == 0) ? wx          : ((d < 0) ? 0.0f : (1.0f - wx));

        float my0 = ((unsigned)y0 < (unsigned)SS) ? 1.0f : 0.0f;
        float my1 = ((unsigned)y1 < (unsigned)SS) ? 1.0f : 0.0f;
        wya[p] = (1.0f - wy) * my0;
        wyb[p] = wy * my1;

        int cy0 = min(max(y0, 0), SS - 1);
        int cy1 = min(max(y1, 0), SS - 1);
        oa[p] = cy0 * SS + bclamp;
        ob[p] = cy1 * SS + bclamp;
    }

    const float* xb = x + (size_t)b * CC * SS * SS;
    size_t obase = (((size_t)b * CC) * SS + ybase) * SS + xc;

    #pragma unroll
    for (int c = 0; c < CC; ++c) {
        const float* img = xb + (size_t)c * SS * SS;

        // ---- 8 independent gathers, program-order pinned: G=8 ----
        f32x2 A0, A1, A2, A3, B0, B1, B2, B3;
        asm volatile("global_load_dwordx2 %0, %1, off" : "=v"(A0) : "v"(img + oa[0]));
        asm volatile("global_load_dwordx2 %0, %1, off" : "=v"(A1) : "v"(img + oa[1]));
        asm volatile("global_load_dwordx2 %0, %1, off" : "=v"(A2) : "v"(img + oa[2]));
        asm volatile("global_load_dwordx2 %0, %1, off" : "=v"(A3) : "v"(img + oa[3]));
        asm volatile("global_load_dwordx2 %0, %1, off" : "=v"(B0) : "v"(img + ob[0]));
        asm volatile("global_load_dwordx2 %0, %1, off" : "=v"(B1) : "v"(img + ob[1]));
        asm volatile("global_load_dwordx2 %0, %1, off" : "=v"(B2) : "v"(img + ob[2]));
        asm volatile("global_load_dwordx2 %0, %1, off" : "=v"(B3) : "v"(img + ob[3]));
        asm volatile("s_waitcnt vmcnt(0)" ::: "memory");
        __builtin_amdgcn_sched_barrier(0);

        // ---- FMAs + coalesced nontemporal stores ----
        f32x2 A[4] = { A0, A1, A2, A3 };
        f32x2 B[4] = { B0, B1, B2, B3 };
        #pragma unroll
        for (int p = 0; p < 4; ++p) {
            float v = wya[p] * (A[p].x * wxa[p] + A[p].y * wxb[p])
                    + wyb[p] * (B[p].x * wxa[p] + B[p].y * wxb[p]);
            __builtin_nontemporal_store(
                v, out + obase + (size_t)c * SS * SS + (size_t)(p * SS));
        }
    }
}

extern "C" void kernel_launch(void* const* d_in, const int* in_sizes, int n_in,
                              void* d_out, int out_size, void* d_ws, size_t ws_size,
                              hipStream_t stream) {
    const float* x        = (const float*)d_in[0];
    const float* offset_x = (const float*)d_in[1];
    const float* offset_y = (const float*)d_in[2];
    const float* weight   = (const float*)d_in[3];
    const void*  max_move = d_in[4];
    float* out = (float*)d_out;
    float* gs  = (float*)d_ws;   // [B][2][G][G] smoothed, scaled, clipped field

    int n1 = BB * 2 * GG * GG;   // 1600
    rds_smooth_kernel<<<(n1 + 255) / 256, 256, 0, stream>>>(
        offset_x, offset_y, weight, max_move, gs);

    int nblocks = BB * (SS / 4) * 4;   // 8192: (b, ytile, xseg)
    rds_deform_kernel<<<nblocks, 256, 0, stream>>>(x, gs, out);
}